// Round 6
// baseline (267.295 us; speedup 1.0000x reference)
//
#include <hip/hip_runtime.h>
#include <math.h>

// Problem constants
#define NNODES 100000
#define MT     64
#define NTILES 1563                     // ceil(100000/64)
#define NODESP (NTILES * MT)            // 100032
#define NEDGES 500000
#define HID    256
#define K2     512
#define GEMM_GRID 256

typedef _Float16 h8v __attribute__((ext_vector_type(8)));
typedef _Float16 h2v __attribute__((ext_vector_type(2)));
typedef __bf16   bf16x8 __attribute__((ext_vector_type(8)));
typedef float    f32x4  __attribute__((ext_vector_type(4)));

__device__ __forceinline__ unsigned short f2bf(float f) {
    unsigned int u = __float_as_uint(f);
    u += 0x7FFFu + ((u >> 16) & 1u);
    return (unsigned short)(u >> 16);
}

// ---- W1 [256][512] fp32 -> Bsw fp16 fragment order (K=256, N=512) ----------
__global__ void cvt_w1h(const float* __restrict__ W1, _Float16* __restrict__ Bsw) {
    int t = blockIdx.x * 256 + threadIdx.x;                  // 8*32*64 = 16384 units
    if (t >= 8 * 32 * 64) return;
    int lane = t & 63, nt = (t >> 6) & 31, kt = t >> 11;
    int j = nt * 16 + (lane & 15);
    int k = kt * 32 + ((lane >> 4) << 3);
    const float* src = W1 + (size_t)(j & 255) * K2 + ((j >> 8) << 8) + k;
    union { _Float16 s[8]; uint4 v; } u;
#pragma unroll
    for (int jj = 0; jj < 8; ++jj) u.s[jj] = (_Float16)src[jj];
    ((uint4*)Bsw)[t] = u.v;
}

// ---- W2 [256] fp32 -> permuted order matching UV's stored column order -----
// stored index t = w*64 + i*4 + nt  <->  hidden col = w*64 + nt*16 + i
__global__ void cvt_w2p(const float* __restrict__ W2, float* __restrict__ w2p) {
    int t = threadIdx.x;                                     // one block of 256
    int i = (t >> 2) & 15, nt = t & 3;
    w2p[t] = W2[(t & ~63) | (nt * 16 + i)];
}

// ---- node GEMM v5: persistent B in regs + double-buffered LDS pipeline -----
// Grid 256 x 512 thr (8 waves, 1 block/CU). Wave w owns cols [w*64,w*64+64).
// Pipeline per tile: issue loads(t+1) -> compute(t from buf) -> store UV(t)
// -> cvt+ds_write(t+1 into other buf) -> barrier. Load latency hides under
// compute+store; one barrier per iteration.
__global__ __launch_bounds__(512, 2) void node_gemm5(
    const float* __restrict__ x,
    const _Float16* __restrict__ Bsw,
    const float* __restrict__ b1,
    _Float16* __restrict__ UV)
{
    __shared__ __align__(16) _Float16 Asw[2][2048 * 8];      // 2 x 32 KB
    const int tid  = threadIdx.x;
    const int lane = tid & 63;
    const int wave = tid >> 6;

    // ---- B into registers (once): 32 x h8v = 128 regs/wave ----
    const h8v* B8 = (const h8v*)Bsw;
    h8v barr[8][4];
#pragma unroll
    for (int ks = 0; ks < 8; ++ks)
#pragma unroll
        for (int nt = 0; nt < 4; ++nt)
            barr[ks][nt] = B8[((size_t)(ks * 32 + wave * 4 + nt)) * 64 + lane];

    float b1v[4];
#pragma unroll
    for (int nt = 0; nt < 4; ++nt) {
        int col = wave * 64 + nt * 16 + (lane & 15);         // true hidden col
        b1v[nt] = (col < 256) ? b1[col] : 0.0f;
    }

    const int k8  = tid & 31;                                // 8-elem k chunk
    const int mh  = tid >> 5;                                // 0..15
    const int ktl = k8 >> 2, q = k8 & 3;

    float4 pa[4], pb[4];                                     // prefetch regs
    auto issue = [&](int tile) {
#pragma unroll
        for (int i = 0; i < 4; ++i) {
            int m   = i * 16 + mh;                           // 0..63
            int row = tile * MT + m;
            int rl  = row < NNODES ? row : 0;
            const float4* p = (const float4*)(x + (size_t)rl * 256 + k8 * 8);
            pa[i] = p[0];
            pb[i] = p[1];
        }
    };
    auto commit = [&](int buf) {
        uint4* A4 = (uint4*)Asw[buf];
#pragma unroll
        for (int i = 0; i < 4; ++i) {
            int m = i * 16 + mh;
            union { _Float16 s[8]; uint4 v; } u;
            u.s[0] = (_Float16)pa[i].x; u.s[1] = (_Float16)pa[i].y;
            u.s[2] = (_Float16)pa[i].z; u.s[3] = (_Float16)pa[i].w;
            u.s[4] = (_Float16)pb[i].x; u.s[5] = (_Float16)pb[i].y;
            u.s[6] = (_Float16)pb[i].z; u.s[7] = (_Float16)pb[i].w;
            int logical = (ktl << 8) + ((m >> 4) << 6) + (q << 4) + (m & 15);
            A4[logical ^ ktl] = u.v;
        }
    };

    int tile = blockIdx.x;                                   // grid 256 <= NTILES
    issue(tile);
    commit(0);
    __syncthreads();
    int buf = 0;

    while (true) {
        int next = tile + GEMM_GRID;
        bool has_next = next < NTILES;
        if (has_next) issue(next);                           // loads in flight

        f32x4 acc[4][4] = {};
        const h8v* A8 = (const h8v*)Asw[buf];
#pragma unroll
        for (int ks = 0; ks < 8; ++ks) {
            h8v af[4];
#pragma unroll
            for (int mt = 0; mt < 4; ++mt)
                af[mt] = A8[(((ks * 4 + mt) << 6) + lane) ^ ks];
#pragma unroll
            for (int mt = 0; mt < 4; ++mt)
#pragma unroll
                for (int nt = 0; nt < 4; ++nt)
                    acc[mt][nt] = __builtin_amdgcn_mfma_f32_16x16x32_f16(
                        af[mt], barr[ks][nt], acc[mt][nt], 0, 0, 0);
        }

        // ---- store tile: permuted cols -> coalesced dwordx2; fold b1 ----
#pragma unroll
        for (int mt = 0; mt < 4; ++mt) {
#pragma unroll
            for (int r = 0; r < 4; ++r) {
                int row = tile * MT + mt * 16 + ((lane >> 4) << 2) + r;
                union { _Float16 h[4]; uint2 v; } pk;
#pragma unroll
                for (int nt = 0; nt < 4; ++nt)
                    pk.h[nt] = (_Float16)(acc[mt][nt][r] + b1v[nt]);
                *(uint2*)(UV + (size_t)row * 512 + wave * 64 + (lane & 15) * 4) = pk.v;
            }
        }

        if (!has_next) break;
        commit(buf ^ 1);                                     // safe: buf^1 last read at t-1
        __syncthreads();                                     // visible for compute(t+1)
        buf ^= 1;
        tile = next;
    }
}

// ---- edge pass v5: packed fp16, 8 edges per 32-lane group ------------------
// Block 256 thr = 8 groups; 64 edges/block; grid 7813 (guard on e).
__global__ __launch_bounds__(256) void edge_out5(
    const _Float16* __restrict__ UV,
    const int* __restrict__ ei,
    const float* __restrict__ w2p,
    const float* __restrict__ b2,
    float* __restrict__ out)
{
    const int tid = threadIdx.x;
    const int q   = tid & 31;
    const int g   = tid >> 5;
    const long e  = ((long)blockIdx.x * 8 + g) * 8;
    if (e >= NEDGES) return;                                 // NEDGES % 8 == 0

    int4 s0 = *(const int4*)(ei + e);
    int4 s1 = *(const int4*)(ei + e + 4);
    int4 d0 = *(const int4*)(ei + NEDGES + e);
    int4 d1 = *(const int4*)(ei + NEDGES + e + 4);
    int is[8] = {s0.x, s0.y, s0.z, s0.w, s1.x, s1.y, s1.z, s1.w};
    int id[8] = {d0.x, d0.y, d0.z, d0.w, d1.x, d1.y, d1.z, d1.w};

    union U8 { uint4 v; h2v h[4]; };
    const _Float16* up = UV + q * 8;

    U8 uu[8], vv[8];
#pragma unroll
    for (int ed = 0; ed < 8; ++ed) {
        uu[ed].v = *(const uint4*)(up + (size_t)is[ed] * 512);
        vv[ed].v = *(const uint4*)(up + (size_t)id[ed] * 512 + 256);
    }

    h2v w2h[4];
    {
        const float4* pw = (const float4*)w2p + q * 2;
        float4 c = pw[0], d = pw[1];
        w2h[0] = h2v{(_Float16)c.x, (_Float16)c.y};
        w2h[1] = h2v{(_Float16)c.z, (_Float16)c.w};
        w2h[2] = h2v{(_Float16)d.x, (_Float16)d.y};
        w2h[3] = h2v{(_Float16)d.z, (_Float16)d.w};
    }

    const h2v zz = {(_Float16)0.0f, (_Float16)0.0f};
    float z[8];
#pragma unroll
    for (int ed = 0; ed < 8; ++ed) {
        float zt = 0.f;
#pragma unroll
        for (int p = 0; p < 4; ++p) {
            h2v h = uu[ed].h[p] + vv[ed].h[p];               // v_pk_add_f16
            h = __builtin_elementwise_max(h, zz);            // v_pk_max_f16
            zt = __builtin_amdgcn_fdot2(h, w2h[p], zt, false);
        }
        z[ed] = zt;
    }
#pragma unroll
    for (int m = 1; m < 32; m <<= 1) {
#pragma unroll
        for (int ed = 0; ed < 8; ++ed)
            z[ed] += __shfl_xor(z[ed], m, 32);
    }
    if (q < 8) {
        float zq = (q == 0) ? z[0] : (q == 1) ? z[1] : (q == 2) ? z[2] :
                   (q == 3) ? z[3] : (q == 4) ? z[4] : (q == 5) ? z[5] :
                   (q == 6) ? z[6] : z[7];
        out[e + q] = 1.0f / (1.0f + expf(-(zq + b2[0])));
    }
}

// ======================= minimal fallback (tiny ws) =========================
__global__ void cvt_w1_r1(const float* __restrict__ W1, unsigned short* __restrict__ Bsw) {
    int t = blockIdx.x * 256 + threadIdx.x;
    if (t >= 16 * 16 * 64) return;
    int lane = t & 63, nt = (t >> 6) & 15, kt = t >> 10;
    int n = nt * 16 + (lane & 15);
    int k = kt * 32 + ((lane >> 4) << 3);
    const float* src = W1 + (size_t)n * K2 + k;
    union { unsigned short s[8]; uint4 v; } u;
#pragma unroll
    for (int j = 0; j < 8; ++j) u.s[j] = f2bf(src[j]);
    ((uint4*)Bsw)[t] = u.v;
}

__global__ __launch_bounds__(256) void edge_mlp_fb(
    const float* __restrict__ xf, const int* __restrict__ ei,
    const unsigned short* __restrict__ Bsw, const float* __restrict__ b1,
    const float* __restrict__ W2, const float* __restrict__ b2,
    float* __restrict__ out)
{
    __shared__ __align__(16) unsigned short Asw[8 * 4 * 64 * 8];
    __shared__ float es[64];
    const int tid = threadIdx.x, lane = tid & 63, wave = tid >> 6;
    const int e0 = blockIdx.x * 64;
    if (tid < 64) es[tid] = 0.0f;
    f32x4 acc[4][4] = {};
    const bf16x8* A8 = (const bf16x8*)Asw;
    const bf16x8* B8 = (const bf16x8*)Bsw;
    for (int h = 0; h < 2; ++h) {
#pragma unroll
        for (int i = 0; i < 8; ++i) {
            int m = i * 8 + wave * 2 + (lane >> 5);
            int e = e0 + m;
            int ee = (e < NEDGES) ? e : 0;
            int node = ei[(size_t)h * NEDGES + ee];
            int chunk = lane & 31;
            const float4* p = (const float4*)(xf + ((size_t)node << 8) + (chunk << 3));
            float4 a = p[0], bq = p[1];
            union { unsigned short s[8]; uint4 v4; } u;
            u.s[0] = f2bf(a.x);  u.s[1] = f2bf(a.y);  u.s[2] = f2bf(a.z);  u.s[3] = f2bf(a.w);
            u.s[4] = f2bf(bq.x); u.s[5] = f2bf(bq.y); u.s[6] = f2bf(bq.z); u.s[7] = f2bf(bq.w);
            int ktl = chunk >> 2, qq = chunk & 3;
            int u16 = ((ktl * 4 + (m >> 4)) << 6) + (qq << 4) + (m & 15);
            u16 ^= (u16 >> 8) & 7;
            ((uint4*)Asw)[u16] = u.v4;
        }
        __syncthreads();
#pragma unroll
        for (int kt = 0; kt < 8; ++kt) {
            bf16x8 af[4], bfr[4];
#pragma unroll
            for (int mt = 0; mt < 4; ++mt) {
                int u16 = ((kt * 4 + mt) << 6) + lane;
                u16 ^= (u16 >> 8) & 7;
                af[mt] = A8[u16];
            }
#pragma unroll
            for (int nt = 0; nt < 4; ++nt)
                bfr[nt] = B8[(((h * 8 + kt) << 4) + (wave << 2) + nt) * 64 + lane];
#pragma unroll
            for (int mt = 0; mt < 4; ++mt)
#pragma unroll
                for (int nt = 0; nt < 4; ++nt)
                    acc[mt][nt] = __builtin_amdgcn_mfma_f32_16x16x32_bf16(
                        af[mt], bfr[nt], acc[mt][nt], 0, 0, 0);
        }
        __syncthreads();
    }
    float w2v[4], b1v[4];
#pragma unroll
    for (int nt = 0; nt < 4; ++nt) {
        int n = (wave << 6) + (nt << 4) + (lane & 15);
        w2v[nt] = W2[n]; b1v[nt] = b1[n];
    }
#pragma unroll
    for (int mt = 0; mt < 4; ++mt) {
#pragma unroll
        for (int r = 0; r < 4; ++r) {
            float p = 0.0f;
#pragma unroll
            for (int nt = 0; nt < 4; ++nt) {
                float hv = acc[mt][nt][r] + b1v[nt];
                p = fmaf(fmaxf(hv, 0.0f), w2v[nt], p);
            }
            p += __shfl_xor(p, 1, 16);
            p += __shfl_xor(p, 2, 16);
            p += __shfl_xor(p, 4, 16);
            p += __shfl_xor(p, 8, 16);
            if ((lane & 15) == 0)
                atomicAdd(&es[(mt << 4) + ((lane >> 4) << 2) + r], p);
        }
    }
    __syncthreads();
    if (tid < 64) {
        int e = e0 + tid;
        if (e < NEDGES) out[e] = 1.0f / (1.0f + expf(-(es[tid] + b2[0])));
    }
}

// ============================== launch ======================================
extern "C" void kernel_launch(void* const* d_in, const int* in_sizes, int n_in,
                              void* d_out, int out_size, void* d_ws, size_t ws_size,
                              hipStream_t stream) {
    const float* x  = (const float*)d_in[0];
    const int*   ei = (const int*)d_in[1];
    const float* W1 = (const float*)d_in[2];
    const float* b1 = (const float*)d_in[3];
    const float* W2 = (const float*)d_in[4];
    const float* b2 = (const float*)d_in[5];
    float* out = (float*)d_out;

    const size_t BSW_BYTES = 1 << 18;                           // 256 KB
    const size_t W2P_BYTES = 4096;
    const size_t UV_BYTES  = (size_t)NODESP * K2 * 2;           // ~102.5 MB
    const size_t NEED_A = BSW_BYTES + W2P_BYTES + UV_BYTES;

    if (ws_size >= NEED_A) {
        _Float16* Bsw = (_Float16*)d_ws;
        float*    w2p = (float*)((char*)d_ws + BSW_BYTES);
        _Float16* UV  = (_Float16*)((char*)d_ws + BSW_BYTES + W2P_BYTES);
        cvt_w1h<<<64, 256, 0, stream>>>(W1, Bsw);
        cvt_w2p<<<1, 256, 0, stream>>>(W2, w2p);
        node_gemm5<<<GEMM_GRID, 512, 0, stream>>>(x, Bsw, b1, UV);
        edge_out5<<<7813, 256, 0, stream>>>(UV, ei, w2p, b2, out);
    } else {
        unsigned short* Bsw = (unsigned short*)d_ws;
        cvt_w1_r1<<<64, 256, 0, stream>>>(W1, Bsw);
        edge_mlp_fb<<<(NEDGES + 63) / 64, 256, 0, stream>>>(x, ei, Bsw, b1, W2, b2, out);
    }
}

// Round 8
// 256.849 us; speedup vs baseline: 1.0407x; 1.0407x over previous
//
#include <hip/hip_runtime.h>
#include <math.h>

// Problem constants
#define NNODES 100000
#define MT     64
#define NTILES 1563                     // ceil(100000/64)
#define NODESP (NTILES * MT)            // 100032
#define NEDGES 500000
#define HID    256
#define K2     512
#define GEMM_GRID 256

typedef _Float16 h8v __attribute__((ext_vector_type(8)));
typedef _Float16 h2v __attribute__((ext_vector_type(2)));
typedef __fp16   fp16x2 __attribute__((ext_vector_type(2)));   // cvt_pkrtz return type
typedef __bf16   bf16x8 __attribute__((ext_vector_type(8)));
typedef float    f32x4  __attribute__((ext_vector_type(4)));

__device__ __forceinline__ unsigned short f2bf(float f) {
    unsigned int u = __float_as_uint(f);
    u += 0x7FFFu + ((u >> 16) & 1u);
    return (unsigned short)(u >> 16);
}
__device__ __forceinline__ void async16(void* lds, const void* g) {
    __builtin_amdgcn_global_load_lds((const __attribute__((address_space(1))) void*)g,
                                     (__attribute__((address_space(3))) void*)lds, 16, 0, 0);
}

// ---- W1 [256][512] fp32 -> Bsw fp16 fragment order (K=256, N=512) ----------
// B[k][j]: j<256 -> W1[j][k] (u weights); j>=256 -> W1[j-256][256+k] (v weights)
// Unit t=(kt*32+nt)*64+lane holds 8 fp16 along k: k=kt*32+(lane>>4)*8+jj, j=nt*16+(lane&15)
__global__ void cvt_w1h(const float* __restrict__ W1, _Float16* __restrict__ Bsw) {
    int t = blockIdx.x * 256 + threadIdx.x;                  // 8*32*64 = 16384 units
    if (t >= 8 * 32 * 64) return;
    int lane = t & 63, nt = (t >> 6) & 31, kt = t >> 11;
    int j = nt * 16 + (lane & 15);
    int k = kt * 32 + ((lane >> 4) << 3);
    const float* src = W1 + (size_t)(j & 255) * K2 + ((j >> 8) << 8) + k;
    union { _Float16 s[8]; uint4 v; } u;
#pragma unroll
    for (int jj = 0; jj < 8; ++jj) u.s[jj] = (_Float16)src[jj];
    ((uint4*)Bsw)[t] = u.v;
}

// ---- W2 [256] fp32 -> permuted order matching UV's stored column order -----
// stored index t = w*64 + i*4 + nt  <->  hidden col = w*64 + nt*16 + i
__global__ void cvt_w2p(const float* __restrict__ W2, float* __restrict__ w2p) {
    int t = threadIdx.x;                                     // one block of 256
    int i = (t >> 2) & 15, nt = t & 3;
    w2p[t] = W2[(t & ~63) | (nt * 16 + i)];
}

// ---- node GEMM v6: persistent B in regs + async fp32 LDS double-buffer ------
// Grid 256 x 512 thr (8 waves, 1 block/CU). Wave w owns cols [w*64,w*64+64):
// B-frags = 32 x h8v = 128 VGPRs, loaded once. A staged as RAW FP32 via
// global_load_lds into fragment-interleaved units (lane-sequential => CF reads),
// converted fp32->fp16 in the k-loop via v_cvt_pkrtz (no prefetch registers!).
// Pipeline per tile: issue async(t+1 -> buf^1), compute(t from buf), store(t),
// one __syncthreads. LDS 2 x 64 KB.
// Unit idx=(ks*4+mt)*2+half (idx in [0,64)), unit holds lane chunk:
//   row = tile*64 + mt*16 + (lane&15), float4 chunk c = ks*8 + (lane>>4)*2 + half
__global__ __launch_bounds__(512, 2) void node_gemm6(
    const float* __restrict__ x,
    const _Float16* __restrict__ Bsw,
    const float* __restrict__ b1,
    _Float16* __restrict__ UV)
{
    __shared__ __align__(16) float Afs[2][64 * 256];         // 2 x 64 KB
    const int tid  = threadIdx.x;
    const int lane = tid & 63;
    const int wave = tid >> 6;

    // ---- B into registers (once): 32 x h8v = 128 regs/wave ----
    const h8v* B8 = (const h8v*)Bsw;
    h8v barr[8][4];
#pragma unroll
    for (int ks = 0; ks < 8; ++ks)
#pragma unroll
        for (int nt = 0; nt < 4; ++nt)
            barr[ks][nt] = B8[((size_t)(ks * 32 + wave * 4 + nt)) * 64 + lane];

    float b1v[4];
#pragma unroll
    for (int nt = 0; nt < 4; ++nt) {
        int col = wave * 64 + nt * 16 + (lane & 15);         // true hidden col
        b1v[nt] = (col < 256) ? b1[col] : 0.0f;
    }

    const int rlo = lane & 15;                               // row-in-mt-tile
    const int chi = (lane >> 4) << 1;                        // k-chunk pair base

    auto issue = [&](int tile, int buf) {
        uint4* A4 = (uint4*)Afs[buf];
#pragma unroll
        for (int i = 0; i < 8; ++i) {
            int idx  = wave * 8 + i;                         // 0..63, wave-uniform
            int ks   = idx >> 3;
            int mt   = (idx >> 1) & 3;
            int half = idx & 1;
            int row  = tile * MT + mt * 16 + rlo;
            int rl   = row < NNODES ? row : 0;
            int c    = ks * 8 + chi + half;                  // float4 chunk 0..63
            async16(&A4[idx * 64], x + (size_t)rl * 256 + c * 4);
        }
    };

    int tile = blockIdx.x;                                   // grid 256 <= NTILES
    issue(tile, 0);
    __syncthreads();
    int buf = 0;

    while (true) {
        int next = tile + GEMM_GRID;
        bool has_next = next < NTILES;
        if (has_next) issue(next, buf ^ 1);                  // async, no wait

        // ---- compute: 8 k-steps; A from LDS fp32 -> cvt_pkrtz -> MFMA ----
        f32x4 acc[4][4] = {};
        const float4* AF = (const float4*)Afs[buf];
#pragma unroll
        for (int ks = 0; ks < 8; ++ks) {
#pragma unroll
            for (int mt = 0; mt < 4; ++mt) {
                int idx = (ks * 4 + mt) * 2;
                float4 r0 = AF[idx * 64 + lane];             // ds_read_b128, CF
                float4 r1 = AF[(idx + 1) * 64 + lane];
                union { fp16x2 p[4]; h8v v; } af;
                af.p[0] = __builtin_amdgcn_cvt_pkrtz(r0.x, r0.y);
                af.p[1] = __builtin_amdgcn_cvt_pkrtz(r0.z, r0.w);
                af.p[2] = __builtin_amdgcn_cvt_pkrtz(r1.x, r1.y);
                af.p[3] = __builtin_amdgcn_cvt_pkrtz(r1.z, r1.w);
#pragma unroll
                for (int nt = 0; nt < 4; ++nt)
                    acc[mt][nt] = __builtin_amdgcn_mfma_f32_16x16x32_f16(
                        af.v, barr[ks][nt], acc[mt][nt], 0, 0, 0);
            }
        }

        // ---- store tile: permuted cols -> coalesced dwordx2; fold b1 ----
#pragma unroll
        for (int mt = 0; mt < 4; ++mt) {
#pragma unroll
            for (int r = 0; r < 4; ++r) {
                int row = tile * MT + mt * 16 + ((lane >> 4) << 2) + r;
                union { _Float16 h[4]; uint2 v; } pk;
#pragma unroll
                for (int nt = 0; nt < 4; ++nt)
                    pk.h[nt] = (_Float16)(acc[mt][nt][r] + b1v[nt]);
                *(uint2*)(UV + (size_t)row * 512 + wave * 64 + (lane & 15) * 4) = pk.v;
            }
        }

        if (!has_next) break;
        __syncthreads();                                     // drains async loads
        buf ^= 1;
        tile = next;
    }
}

// ---- edge pass v5: packed fp16, 8 edges per 32-lane group ------------------
__global__ __launch_bounds__(256) void edge_out5(
    const _Float16* __restrict__ UV,
    const int* __restrict__ ei,
    const float* __restrict__ w2p,
    const float* __restrict__ b2,
    float* __restrict__ out)
{
    const int tid = threadIdx.x;
    const int q   = tid & 31;
    const int g   = tid >> 5;
    const long e  = ((long)blockIdx.x * 8 + g) * 8;
    if (e >= NEDGES) return;                                 // NEDGES % 8 == 0

    int4 s0 = *(const int4*)(ei + e);
    int4 s1 = *(const int4*)(ei + e + 4);
    int4 d0 = *(const int4*)(ei + NEDGES + e);
    int4 d1 = *(const int4*)(ei + NEDGES + e + 4);
    int is[8] = {s0.x, s0.y, s0.z, s0.w, s1.x, s1.y, s1.z, s1.w};
    int id[8] = {d0.x, d0.y, d0.z, d0.w, d1.x, d1.y, d1.z, d1.w};

    union U8 { uint4 v; h2v h[4]; };
    const _Float16* up = UV + q * 8;

    U8 uu[8], vv[8];
#pragma unroll
    for (int ed = 0; ed < 8; ++ed) {
        uu[ed].v = *(const uint4*)(up + (size_t)is[ed] * 512);
        vv[ed].v = *(const uint4*)(up + (size_t)id[ed] * 512 + 256);
    }

    h2v w2h[4];
    {
        const float4* pw = (const float4*)w2p + q * 2;
        float4 c = pw[0], d = pw[1];
        w2h[0] = h2v{(_Float16)c.x, (_Float16)c.y};
        w2h[1] = h2v{(_Float16)c.z, (_Float16)c.w};
        w2h[2] = h2v{(_Float16)d.x, (_Float16)d.y};
        w2h[3] = h2v{(_Float16)d.z, (_Float16)d.w};
    }

    const h2v zz = {(_Float16)0.0f, (_Float16)0.0f};
    float z[8];
#pragma unroll
    for (int ed = 0; ed < 8; ++ed) {
        float zt = 0.f;
#pragma unroll
        for (int p = 0; p < 4; ++p) {
            h2v h = uu[ed].h[p] + vv[ed].h[p];               // v_pk_add_f16
            h = __builtin_elementwise_max(h, zz);            // v_pk_max_f16
            zt = __builtin_amdgcn_fdot2(h, w2h[p], zt, false);
        }
        z[ed] = zt;
    }
#pragma unroll
    for (int m = 1; m < 32; m <<= 1) {
#pragma unroll
        for (int ed = 0; ed < 8; ++ed)
            z[ed] += __shfl_xor(z[ed], m, 32);
    }
    if (q < 8) {
        float zq = (q == 0) ? z[0] : (q == 1) ? z[1] : (q == 2) ? z[2] :
                   (q == 3) ? z[3] : (q == 4) ? z[4] : (q == 5) ? z[5] :
                   (q == 6) ? z[6] : z[7];
        out[e + q] = 1.0f / (1.0f + expf(-(zq + b2[0])));
    }
}

// ======================= minimal fallback (tiny ws) =========================
__global__ void cvt_w1_r1(const float* __restrict__ W1, unsigned short* __restrict__ Bsw) {
    int t = blockIdx.x * 256 + threadIdx.x;
    if (t >= 16 * 16 * 64) return;
    int lane = t & 63, nt = (t >> 6) & 15, kt = t >> 10;
    int n = nt * 16 + (lane & 15);
    int k = kt * 32 + ((lane >> 4) << 3);
    const float* src = W1 + (size_t)n * K2 + k;
    union { unsigned short s[8]; uint4 v; } u;
#pragma unroll
    for (int j = 0; j < 8; ++j) u.s[j] = f2bf(src[j]);
    ((uint4*)Bsw)[t] = u.v;
}

__global__ __launch_bounds__(256) void edge_mlp_fb(
    const float* __restrict__ xf, const int* __restrict__ ei,
    const unsigned short* __restrict__ Bsw, const float* __restrict__ b1,
    const float* __restrict__ W2, const float* __restrict__ b2,
    float* __restrict__ out)
{
    __shared__ __align__(16) unsigned short Asw[8 * 4 * 64 * 8];
    __shared__ float es[64];
    const int tid = threadIdx.x, lane = tid & 63, wave = tid >> 6;
    const int e0 = blockIdx.x * 64;
    if (tid < 64) es[tid] = 0.0f;
    f32x4 acc[4][4] = {};
    const bf16x8* A8 = (const bf16x8*)Asw;
    const bf16x8* B8 = (const bf16x8*)Bsw;
    for (int h = 0; h < 2; ++h) {
#pragma unroll
        for (int i = 0; i < 8; ++i) {
            int m = i * 8 + wave * 2 + (lane >> 5);
            int e = e0 + m;
            int ee = (e < NEDGES) ? e : 0;
            int node = ei[(size_t)h * NEDGES + ee];
            int chunk = lane & 31;
            const float4* p = (const float4*)(xf + ((size_t)node << 8) + (chunk << 3));
            float4 a = p[0], bq = p[1];
            union { unsigned short s[8]; uint4 v4; } u;
            u.s[0] = f2bf(a.x);  u.s[1] = f2bf(a.y);  u.s[2] = f2bf(a.z);  u.s[3] = f2bf(a.w);
            u.s[4] = f2bf(bq.x); u.s[5] = f2bf(bq.y); u.s[6] = f2bf(bq.z); u.s[7] = f2bf(bq.w);
            int ktl = chunk >> 2, qq = chunk & 3;
            int u16 = ((ktl * 4 + (m >> 4)) << 6) + (qq << 4) + (m & 15);
            u16 ^= (u16 >> 8) & 7;
            ((uint4*)Asw)[u16] = u.v4;
        }
        __syncthreads();
#pragma unroll
        for (int kt = 0; kt < 8; ++kt) {
            bf16x8 af[4], bfr[4];
#pragma unroll
            for (int mt = 0; mt < 4; ++mt) {
                int u16 = ((kt * 4 + mt) << 6) + lane;
                u16 ^= (u16 >> 8) & 7;
                af[mt] = A8[u16];
            }
#pragma unroll
            for (int nt = 0; nt < 4; ++nt)
                bfr[nt] = B8[(((h * 8 + kt) << 4) + (wave << 2) + nt) * 64 + lane];
#pragma unroll
            for (int mt = 0; mt < 4; ++mt)
#pragma unroll
                for (int nt = 0; nt < 4; ++nt)
                    acc[mt][nt] = __builtin_amdgcn_mfma_f32_16x16x32_bf16(
                        af[mt], bfr[nt], acc[mt][nt], 0, 0, 0);
        }
        __syncthreads();
    }
    float w2v[4], b1v[4];
#pragma unroll
    for (int nt = 0; nt < 4; ++nt) {
        int n = (wave << 6) + (nt << 4) + (lane & 15);
        w2v[nt] = W2[n]; b1v[nt] = b1[n];
    }
#pragma unroll
    for (int mt = 0; mt < 4; ++mt) {
#pragma unroll
        for (int r = 0; r < 4; ++r) {
            float p = 0.0f;
#pragma unroll
            for (int nt = 0; nt < 4; ++nt) {
                float hv = acc[mt][nt][r] + b1v[nt];
                p = fmaf(fmaxf(hv, 0.0f), w2v[nt], p);
            }
            p += __shfl_xor(p, 1, 16);
            p += __shfl_xor(p, 2, 16);
            p += __shfl_xor(p, 4, 16);
            p += __shfl_xor(p, 8, 16);
            if ((lane & 15) == 0)
                atomicAdd(&es[(mt << 4) + ((lane >> 4) << 2) + r], p);
        }
    }
    __syncthreads();
    if (tid < 64) {
        int e = e0 + tid;
        if (e < NEDGES) out[e] = 1.0f / (1.0f + expf(-(es[tid] + b2[0])));
    }
}

// ============================== launch ======================================
extern "C" void kernel_launch(void* const* d_in, const int* in_sizes, int n_in,
                              void* d_out, int out_size, void* d_ws, size_t ws_size,
                              hipStream_t stream) {
    const float* x  = (const float*)d_in[0];
    const int*   ei = (const int*)d_in[1];
    const float* W1 = (const float*)d_in[2];
    const float* b1 = (const float*)d_in[3];
    const float* W2 = (const float*)d_in[4];
    const float* b2 = (const float*)d_in[5];
    float* out = (float*)d_out;

    const size_t BSW_BYTES = 1 << 18;                           // 256 KB
    const size_t W2P_BYTES = 4096;
    const size_t UV_BYTES  = (size_t)NODESP * K2 * 2;           // ~102.5 MB
    const size_t NEED_A = BSW_BYTES + W2P_BYTES + UV_BYTES;

    if (ws_size >= NEED_A) {
        _Float16* Bsw = (_Float16*)d_ws;
        float*    w2p = (float*)((char*)d_ws + BSW_BYTES);
        _Float16* UV  = (_Float16*)((char*)d_ws + BSW_BYTES + W2P_BYTES);
        cvt_w1h<<<64, 256, 0, stream>>>(W1, Bsw);
        cvt_w2p<<<1, 256, 0, stream>>>(W2, w2p);
        node_gemm6<<<GEMM_GRID, 512, 0, stream>>>(x, Bsw, b1, UV);
        edge_out5<<<7813, 256, 0, stream>>>(UV, ei, w2p, b2, out);
    } else {
        unsigned short* Bsw = (unsigned short*)d_ws;
        cvt_w1_r1<<<64, 256, 0, stream>>>(W1, Bsw);
        edge_mlp_fb<<<(NEDGES + 63) / 64, 256, 0, stream>>>(x, ei, Bsw, b1, W2, b2, out);
    }
}